// Round 4
// baseline (11779.269 us; speedup 1.0000x reference)
//
#include <hip/hip_runtime.h>

#define NB 64      // batch
#define NS 512     // seq len
#define NE 512     // emb dim
#define NH 512     // per-dir hidden
#define NG 2048    // 4*NH
#define NT 64      // tags
#define KC 1024    // combined K = NE + NH
#define HW32 8388608u   // u32 words per direction in HALL: 512*32*512
#define SENT 0x7FC07FC0u  // bf16 NaN|NaN — unreachable for h=tanh*sigmoid
#define NEGV (-10000.0f)

typedef __attribute__((ext_vector_type(8))) short bf16x8;
typedef __attribute__((ext_vector_type(4))) float f32x4;
typedef unsigned short u16;
typedef unsigned int u32;

__device__ __forceinline__ u16 f2bf(float x) {
    unsigned u = __builtin_bit_cast(unsigned, x);
    u += 0x7fffu + ((u >> 16) & 1u);
    return (u16)(u >> 16);
}
__device__ __forceinline__ float sig_(float x) { return 1.0f / (1.0f + expf(-x)); }

// ---------- prep: combined [W_ih | W_hh] -> bf16, [2][2048][1024] ----------
__global__ void prep_wcomb(const float* __restrict__ wihf, const float* __restrict__ whhf,
                           const float* __restrict__ wihb, const float* __restrict__ whhb,
                           u16* __restrict__ wcomb) {
    int idx = blockIdx.x * 256 + threadIdx.x;   // 1,048,576 threads, 4 elems each
    int base = idx * 4;
    int d = base >> 21;
    int rem = base & ((1 << 21) - 1);
    int n = rem >> 10;
    int k = rem & 1023;
    const float* wih = d ? wihb : wihf;
    const float* whh = d ? whhb : whhf;
    const float* src = (k < NE) ? (wih + n * NE + k) : (whh + n * NH + (k - NE));
    float4 v = *reinterpret_cast<const float4*>(src);
    ushort4 o;
    o.x = f2bf(v.x); o.y = f2bf(v.y); o.z = f2bf(v.z); o.w = f2bf(v.w);
    *reinterpret_cast<ushort4*>(wcomb + base) = o;
}

// ---------- prep: w_out->bf16, bias = b_ih+b_hh ----------
__global__ void prep_misc(const float* __restrict__ wout,
                          const float* __restrict__ bihf, const float* __restrict__ bhhf,
                          const float* __restrict__ bihb, const float* __restrict__ bhhb,
                          u16* __restrict__ woutbf, float* __restrict__ bias) {
    int idx = blockIdx.x * 256 + threadIdx.x;   // 272 blocks = 69,632 threads
    if (idx < 65536) { woutbf[idx] = f2bf(wout[idx]); return; }
    idx -= 65536;
    if (idx < 4096) {
        int d = idx >> 11, g = idx & 2047;
        bias[idx] = d ? (bihb[g] + bhhb[g]) : (bihf[g] + bhhf[g]);
    }
}

// ---------- prep: sentinel-fill HALL (64 MiB) ----------
__global__ void prep_hfill(uint4* __restrict__ h) {
    int idx = blockIdx.x * 256 + threadIdx.x;   // 16384 blocks -> 4,194,304 threads
    uint4 v = {SENT, SENT, SENT, SENT};
    h[idx] = v;
}

// ---------- prep: embedding gather -> x_bf[(s*64+b)][512] bf16 ----------
__global__ void prep_embed(const float* __restrict__ emb, const int* __restrict__ sents,
                           u16* __restrict__ xbf) {
    int idx = blockIdx.x * 256 + threadIdx.x;   // 4,194,304 threads, 4 elems each
    int m = idx >> 7;
    int e = (idx & 127) << 2;
    int s = m >> 6, b = m & 63;
    int tok = sents[b * NS + s];
    float4 v = *reinterpret_cast<const float4*>(emb + (size_t)tok * NE + e);
    ushort4 o;
    o.x = f2bf(v.x); o.y = f2bf(v.y); o.z = f2bf(v.z); o.w = f2bf(v.w);
    *reinterpret_cast<ushort4*>(xbf + (size_t)m * NE + e) = o;
}

// ---------- persistent bi-LSTM: grid (32 jblk, 2 dir), 512 thr ----------
// HALL (u32 view): [dir][s][jblk][bb(64)][8 j-pair words]. No flags: consumers
// poll the data itself against SENT. Weights live in VGPRs (B-fragments).
// One __syncthreads per step (double-buffered gred).
__global__ __launch_bounds__(512, 1)
void lstm_persist(const u16* __restrict__ xbf, const u16* __restrict__ wcomb,
                  const float* __restrict__ bias, u32* __restrict__ hallw) {
    const int jblk = blockIdx.x;   // 0..31 -> j slice of 16
    const int dir  = blockIdx.y;   // 0 fwd, 1 bwd
    const int t = threadIdx.x;
    const int w = t >> 6, l = t & 63;
    const int l16 = l & 15, lhi = l >> 4;
    const int kw = w & 3;          // K-slice of 256
    const int nh = w >> 2;         // gate-half: 0 -> gates i,f ; 1 -> gates g,o
    const int kbase = kw * 256;
    const bool isx = (kw < 2);

    __shared__ float gred[2][4][64][67];   // 137 KiB, parity double-buffered

    // ---- B-fragments in registers (once): 2 n-frags x 8 k-tiles ----
    bf16x8 bfrag[2][8];
#pragma unroll
    for (int nf = 0; nf < 2; ++nf)
#pragma unroll
        for (int kt = 0; kt < 8; ++kt) {
            int gr = (nh * 2 + nf) * NH + jblk * 16 + l16;
            int k = kbase + kt * 32 + lhi * 8;
            bfrag[nf][kt] = *reinterpret_cast<const bf16x8*>(
                wcomb + (size_t)(dir * NG + gr) * KC + k);
        }

    // ---- epilogue ownership: thread -> (bb = t>>3, j-pair p = t&7) ----
    const int bb = t >> 3;
    const int p  = t & 7;
    const int jj = p * 2;
    float breg[4][2];
#pragma unroll
    for (int gi = 0; gi < 4; ++gi)
#pragma unroll
        for (int u = 0; u < 2; ++u)
            breg[gi][u] = bias[dir * NG + gi * NH + jblk * 16 + jj + u];
    float c0 = 0.f, c1 = 0.f;

    u32* H = hallw + (size_t)dir * HW32;

    for (int step = 0; step < NS; ++step) {
        const int s = dir ? (NS - 1 - step) : step;
        const int sprev = dir ? (s + 1) : (s - 1);
        const int par = step & 1;

        f32x4 acc[4][2];
#pragma unroll
        for (int mf = 0; mf < 4; ++mf)
#pragma unroll
            for (int nf = 0; nf < 2; ++nf)
                acc[mf][nf] = (f32x4){0.f, 0.f, 0.f, 0.f};

        if (isx) {
            const u16* Abase = xbf + (size_t)(s * NB) * NE + kbase;
#pragma unroll
            for (int kt = 0; kt < 8; ++kt) {
                int k = kt * 32 + lhi * 8;
#pragma unroll
                for (int mf = 0; mf < 4; ++mf) {
                    bf16x8 a = *reinterpret_cast<const bf16x8*>(Abase + (size_t)(mf * 16 + l16) * NE + k);
                    acc[mf][0] = __builtin_amdgcn_mfma_f32_16x16x32_bf16(a, bfrag[0][kt], acc[mf][0], 0, 0, 0);
                    acc[mf][1] = __builtin_amdgcn_mfma_f32_16x16x32_bf16(a, bfrag[1][kt], acc[mf][1], 0, 0, 0);
                }
            }
        } else if (step > 0) {
            const int kloc = kbase - 512;
#pragma unroll
            for (int kt = 0; kt < 8; ++kt) {
                int j0 = kloc + kt * 32 + lhi * 8;
                u32 abase = (u32)(sprev * 32 + (j0 >> 4)) * 512u + (u32)((j0 & 15) >> 1);
                u32 d[4][4];
                for (;;) {           // sentinel poll: data IS the flag
                    u32 bad = 0;
#pragma unroll
                    for (int mf = 0; mf < 4; ++mf) {
                        u32 a0 = abase + (u32)(mf * 16 + l16) * 8u;
#pragma unroll
                        for (int q = 0; q < 4; ++q) {
                            d[mf][q] = __hip_atomic_load(H + a0 + q, __ATOMIC_RELAXED,
                                                         __HIP_MEMORY_SCOPE_AGENT);
                            bad |= (u32)(d[mf][q] == SENT);
                        }
                    }
                    if (!__ballot(bad)) break;
                }
#pragma unroll
                for (int mf = 0; mf < 4; ++mf) {
                    union { u32 u[4]; bf16x8 v; } cv;
                    cv.u[0] = d[mf][0]; cv.u[1] = d[mf][1];
                    cv.u[2] = d[mf][2]; cv.u[3] = d[mf][3];
                    acc[mf][0] = __builtin_amdgcn_mfma_f32_16x16x32_bf16(cv.v, bfrag[0][kt], acc[mf][0], 0, 0, 0);
                    acc[mf][1] = __builtin_amdgcn_mfma_f32_16x16x32_bf16(cv.v, bfrag[1][kt], acc[mf][1], 0, 0, 0);
                }
            }
        }

        // ---- dump partials (parity buffer) ----
#pragma unroll
        for (int mf = 0; mf < 4; ++mf)
#pragma unroll
            for (int nf = 0; nf < 2; ++nf)
#pragma unroll
                for (int r = 0; r < 4; ++r)
                    gred[par][kw][mf * 16 + lhi * 4 + r][nh * 32 + nf * 16 + l16] = acc[mf][nf][r];
        __syncthreads();   // the ONLY barrier per step

        // ---- reduce K-partials + cell update (c in regs) ----
        float g[2][4];
#pragma unroll
        for (int u = 0; u < 2; ++u)
#pragma unroll
            for (int gi = 0; gi < 4; ++gi) {
                int n = gi * 16 + jj + u;
                g[u][gi] = gred[par][0][bb][n] + gred[par][1][bb][n]
                         + gred[par][2][bb][n] + gred[par][3][bb][n] + breg[gi][u];
            }
        float cn0 = sig_(g[0][1]) * c0 + sig_(g[0][0]) * tanhf(g[0][2]);
        float cn1 = sig_(g[1][1]) * c1 + sig_(g[1][0]) * tanhf(g[1][2]);
        c0 = cn0; c1 = cn1;
        u32 hw = (u32)f2bf(sig_(g[0][3]) * tanhf(cn0))
               | ((u32)f2bf(sig_(g[1][3]) * tanhf(cn1)) << 16);
        // fire-and-forget publish: [s][jblk][bb][p] ; word index == t
        __hip_atomic_store(H + (u32)(s * 32 + jblk) * 512u + (u32)t, hw,
                           __ATOMIC_RELAXED, __HIP_MEMORY_SCOPE_AGENT);
        // no second barrier: next step dumps into gred[par^1]
    }
}

// ---------- emissions: one block per s; rows b=0..63 ----------
__global__ void emis_kernel(const u32* __restrict__ hallw, const u16* __restrict__ woutbf,
                            const float* __restrict__ bout, float* __restrict__ emis) {
    const int blk = blockIdx.x;                   // = s, 512 blocks
    const int t = threadIdx.x;
    const int w = t >> 6, l = t & 63;
    const int l16 = l & 15, lhi = l >> 4;
    const int b = w * 16 + l16;

    const u32* hf = hallw + (size_t)blk * (32 * 512);   // dir 0, step blk
    const u32* hbk = hf + HW32;                          // dir 1
    const u16* br0 = woutbf + (size_t)(0 * 16 + l16) * KC;
    const u16* br1 = woutbf + (size_t)(1 * 16 + l16) * KC;
    const u16* br2 = woutbf + (size_t)(2 * 16 + l16) * KC;
    const u16* br3 = woutbf + (size_t)(3 * 16 + l16) * KC;

    f32x4 a0 = {0.f,0.f,0.f,0.f}, a1 = {0.f,0.f,0.f,0.f}, a2 = {0.f,0.f,0.f,0.f}, a3 = {0.f,0.f,0.f,0.f};
#pragma unroll
    for (int kt = 0; kt < 16; ++kt) {             // h_f part
        int k = kt * 32 + lhi * 8;                // = j0
        bf16x8 a = *reinterpret_cast<const bf16x8*>(hf + (size_t)(k >> 4) * 512 + b * 8 + ((k & 15) >> 1));
        a0 = __builtin_amdgcn_mfma_f32_16x16x32_bf16(a, *reinterpret_cast<const bf16x8*>(br0 + k), a0, 0, 0, 0);
        a1 = __builtin_amdgcn_mfma_f32_16x16x32_bf16(a, *reinterpret_cast<const bf16x8*>(br1 + k), a1, 0, 0, 0);
        a2 = __builtin_amdgcn_mfma_f32_16x16x32_bf16(a, *reinterpret_cast<const bf16x8*>(br2 + k), a2, 0, 0, 0);
        a3 = __builtin_amdgcn_mfma_f32_16x16x32_bf16(a, *reinterpret_cast<const bf16x8*>(br3 + k), a3, 0, 0, 0);
    }
#pragma unroll
    for (int kt = 0; kt < 16; ++kt) {             // h_b part
        int k = kt * 32 + lhi * 8;
        bf16x8 a = *reinterpret_cast<const bf16x8*>(hbk + (size_t)(k >> 4) * 512 + b * 8 + ((k & 15) >> 1));
        a0 = __builtin_amdgcn_mfma_f32_16x16x32_bf16(a, *reinterpret_cast<const bf16x8*>(br0 + NH + k), a0, 0, 0, 0);
        a1 = __builtin_amdgcn_mfma_f32_16x16x32_bf16(a, *reinterpret_cast<const bf16x8*>(br1 + NH + k), a1, 0, 0, 0);
        a2 = __builtin_amdgcn_mfma_f32_16x16x32_bf16(a, *reinterpret_cast<const bf16x8*>(br2 + NH + k), a2, 0, 0, 0);
        a3 = __builtin_amdgcn_mfma_f32_16x16x32_bf16(a, *reinterpret_cast<const bf16x8*>(br3 + NH + k), a3, 0, 0, 0);
    }
#pragma unroll
    for (int r = 0; r < 4; ++r) {
        int gm = blk * 64 + w * 16 + lhi * 4 + r;
        emis[(size_t)gm * NT + 0 * 16 + l16] = a0[r] + bout[0 * 16 + l16];
        emis[(size_t)gm * NT + 1 * 16 + l16] = a1[r] + bout[1 * 16 + l16];
        emis[(size_t)gm * NT + 2 * 16 + l16] = a2[r] + bout[2 * 16 + l16];
        emis[(size_t)gm * NT + 3 * 16 + l16] = a3[r] + bout[3 * 16 + l16];
    }
}

// ---------- gold score per batch ----------
__global__ void gold_kernel(const float* __restrict__ emis, const int* __restrict__ tags,
                            const float* __restrict__ trans, float* __restrict__ gold) {
    int b = blockIdx.x, t = threadIdx.x;
    float acc = 0.f;
    for (int s = t; s < NS; s += 256) {
        int tag = tags[b * NS + s];
        int prev = (s == 0) ? 0 : tags[b * NS + s - 1];
        acc += emis[(size_t)(s * NB + b) * NT + tag] + trans[tag * NT + prev];
    }
    acc += __shfl_xor(acc, 1);  acc += __shfl_xor(acc, 2);  acc += __shfl_xor(acc, 4);
    acc += __shfl_xor(acc, 8);  acc += __shfl_xor(acc, 16); acc += __shfl_xor(acc, 32);
    __shared__ float red[4];
    if ((t & 63) == 0) red[t >> 6] = acc;
    __syncthreads();
    if (t == 0) gold[b] = red[0] + red[1] + red[2] + red[3];
}

// ---------- CRF forward (log partition) per batch ----------
__global__ void crf_kernel(const float* __restrict__ emis, const float* __restrict__ trans,
                           float* __restrict__ fwd) {
    int b = blockIdx.x, t = threadIdx.x;
    __shared__ float transT[64][65];   // [prev][next]
    __shared__ float alA[64], alB[64];
    for (int idx = t; idx < 4096; idx += 256) {
        int next = idx & 63, prev = idx >> 6;
        transT[prev][next] = trans[next * NT + prev];
    }
    if (t < 64) alA[t] = (t == 0) ? 0.f : NEGV;
    __syncthreads();

    int next = t >> 2, q = t & 3;
    float* cur = alA;
    float* nxt = alB;
    for (int s = 0; s < NS; ++s) {
        float emit = emis[(size_t)(s * NB + b) * NT + next];
        int p0 = q * 16;
        float M = -3.0e38f;
#pragma unroll
        for (int i = 0; i < 16; ++i) {
            float v = cur[p0 + i] + transT[p0 + i][next];
            M = fmaxf(M, v);
        }
        M = fmaxf(M, __shfl_xor(M, 1));
        M = fmaxf(M, __shfl_xor(M, 2));
        float Ssum = 0.f;
#pragma unroll
        for (int i = 0; i < 16; ++i) {
            float v = cur[p0 + i] + transT[p0 + i][next];
            Ssum += expf(v - M);
        }
        Ssum += __shfl_xor(Ssum, 1);
        Ssum += __shfl_xor(Ssum, 2);
        if (q == 0) nxt[next] = M + logf(Ssum) + emit;
        __syncthreads();
        float* tmp = cur; cur = nxt; nxt = tmp;
    }
    if (t < 64) {
        float v = cur[t];
        float M = v;
        for (int d = 1; d < 64; d <<= 1) M = fmaxf(M, __shfl_xor(M, d));
        float e = expf(v - M);
        for (int d = 1; d < 64; d <<= 1) e += __shfl_xor(e, d);
        if (t == 0) fwd[b] = M + logf(e);
    }
}

// ---------- final: mean(fwd - gold) ----------
__global__ void final_kernel(const float* __restrict__ fwd, const float* __restrict__ gold,
                             float* __restrict__ out) {
    int t = threadIdx.x;   // 64
    float v = fwd[t] - gold[t];
    for (int d = 1; d < 64; d <<= 1) v += __shfl_xor(v, d);
    if (t == 0) out[0] = v * (1.0f / 64.0f);
}

extern "C" void kernel_launch(void* const* d_in, const int* in_sizes, int n_in,
                              void* d_out, int out_size, void* d_ws, size_t ws_size,
                              hipStream_t stream) {
    (void)in_sizes; (void)n_in; (void)out_size; (void)ws_size;
    const int* sents = (const int*)d_in[0];
    const int* tags  = (const int*)d_in[1];
    const float* emb  = (const float*)d_in[3];
    const float* wihf = (const float*)d_in[4];
    const float* whhf = (const float*)d_in[5];
    const float* bihf = (const float*)d_in[6];
    const float* bhhf = (const float*)d_in[7];
    const float* wihb = (const float*)d_in[8];
    const float* whhb = (const float*)d_in[9];
    const float* bihb = (const float*)d_in[10];
    const float* bhhb = (const float*)d_in[11];
    const float* wout = (const float*)d_in[12];
    const float* bout = (const float*)d_in[13];
    const float* trans = (const float*)d_in[14];

    char* ws = (char*)d_ws;
    u16*   WCOMB  = (u16*)(ws + 0);              //  8 MiB  [2][2048][1024] bf16
    u16*   WOUTBF = (u16*)(ws + 8388608);        //  128 KiB [64][1024] bf16
    float* BIAS   = (float*)(ws + 8519680);      //  16 KiB  [2][2048] f32
    u16*   XBF    = (u16*)(ws + 8536064);        //  32 MiB  [32768][512] bf16
    u32*   HALLW  = (u32*)(ws + 42090496);       //  64 MiB  [2][512][32][64][8w] u32
    float* EMIS   = (float*)(ws + 109199360);    //  8 MiB   [512*64][64] f32
    float* FWD    = (float*)(ws + 117587968);    //  [64] f32
    float* GOLD   = (float*)(ws + 117588224);    //  [64] f32

    prep_wcomb<<<4096, 256, 0, stream>>>(wihf, whhf, wihb, whhb, WCOMB);
    prep_misc<<<272, 256, 0, stream>>>(wout, bihf, bhhf, bihb, bhhb, WOUTBF, BIAS);
    prep_hfill<<<16384, 256, 0, stream>>>((uint4*)HALLW);
    prep_embed<<<16384, 256, 0, stream>>>(emb, sents, XBF);

    lstm_persist<<<dim3(32, 2), 512, 0, stream>>>(XBF, WCOMB, BIAS, HALLW);

    emis_kernel<<<512, 256, 0, stream>>>(HALLW, WOUTBF, bout, EMIS);
    gold_kernel<<<64, 256, 0, stream>>>(EMIS, tags, trans, GOLD);
    crf_kernel<<<64, 256, 0, stream>>>(EMIS, trans, FWD);
    final_kernel<<<1, 64, 0, stream>>>(FWD, GOLD, (float*)d_out);
}